// Round 22
// baseline (67.952 us; speedup 1.0000x reference)
//
#include <hip/hip_runtime.h>
#include <hip/hip_bf16.h>
#include <math.h>

#define B_  4096u
#define N_  8192
#define D_  128
#define M_  8190u          // negatives per logits row = 2B-2
#define SB_ 25159680u      // S_B = B*(2B-2) - B*(B-1)/2
#define NT2_ 1056          // upper-tri 128x256 tiles

#define AS1 __attribute__((address_space(1)))
#define AS3 __attribute__((address_space(3)))

typedef __attribute__((ext_vector_type(8))) int   i32x8;
typedef __attribute__((ext_vector_type(4))) int   i32x4;
typedef __attribute__((ext_vector_type(4))) float f32x4;

// cumulative flat-count of strict-upper (minus positives) elements before row i
static __device__ __forceinline__ unsigned rowS(unsigned i) {
  if (i <= B_) return i * (2u * B_ - 2u) - (i * (i - 1u)) / 2u;
  unsigned d = i - B_;
  return SB_ + d * (B_ - 1u) - (d * (d - 1u)) / 2u;
}
// cumulative tile count before row-panel m (128-row panels, 256-col tiles)
static __device__ __forceinline__ int tile0(int m) {
  return 32 * m - (m * m - 2 * m + (m & 1)) / 4;
}
// 16-lane DPP row_ror rotation reduce (validated R7/R8)
template <int CTRL>
static __device__ __forceinline__ float dpp_add(float x) {
  union { float f; int i; } u, r;
  u.f = x;
  r.i = __builtin_amdgcn_mov_dpp(u.i, CTRL, 0xF, 0xF, 0);
  return x + r.f;
}
static __device__ __forceinline__ float rsum16(float x) {
  x = dpp_add<0x121>(x);
  x = dpp_add<0x122>(x);
  x = dpp_add<0x124>(x);
  x = dpp_add<0x128>(x);
  return x;
}

// ---------------------------------------------------------------------------
// Kernel A: normalize rows of reps=[zjs;zis] -> fp8 e4m3 nb[row][k] (1 MB);
// build Trow; block 0 zeroes the completion counter (replay-safe).
// (R19 form; only the zero-fill shrank — global E no longer exists)
// ---------------------------------------------------------------------------
__global__ __launch_bounds__(256) void nt_norm(
    const float* __restrict__ zis, const float* __restrict__ zjs,
    unsigned* __restrict__ nb8, unsigned* __restrict__ Trow,
    unsigned* __restrict__ counter) {
  const int t   = threadIdx.x;
  const int row = blockIdx.x * 8 + (t >> 5);
  const int c   = t & 31;
  const float* src = (row < (int)B_) ? (zjs + (size_t)row * D_)
                                     : (zis + (size_t)(row - (int)B_) * D_);
  float4 v = *(const float4*)(src + c * 4);
  float s = v.x * v.x + v.y * v.y + v.z * v.z + v.w * v.w;
  #pragma unroll
  for (int m = 16; m >= 1; m >>= 1) s += __shfl_xor(s, m, 32);
  float rn = 1.0f / fmaxf(sqrtf(s), 1e-8f);
  int p = __builtin_amdgcn_cvt_pk_fp8_f32(v.x * rn, v.y * rn, 0, false);
  p     = __builtin_amdgcn_cvt_pk_fp8_f32(v.z * rn, v.w * rn, p, true);
  nb8[(size_t)row * 32 + c] = (unsigned)p;

  if (t < 8) {
    unsigned i   = (unsigned)(blockIdx.x * 8 + t);
    unsigned S   = rowS(i);
    unsigned rlo = S / M_;
    unsigned Sh  = (rlo + 1u) * M_;
    unsigned jt  = Sh - S + i + 1u;
    Trow[i] = jt + ((i < B_ && jt > i + B_) ? 1u : 0u);
  }
  if (blockIdx.x == 0 && t == 0) *counter = 0u;
}

// ---------------------------------------------------------------------------
// Kernel B: 128x256-tile upper-tri Gram via MX-scaled fp8 MFMA
// (byte-identical to R15/R19 — proven best, measured 19.0 us steady-state).
// ---------------------------------------------------------------------------
__global__ __launch_bounds__(512, 4) void nt_gemm(
    const char* __restrict__ nb, const unsigned* __restrict__ Trow,
    float2* __restrict__ part, float* __restrict__ posl) {
  // XCD-chunked bijective swizzle: 1056 = 8 * 132
  const int tb = ((int)blockIdx.x & 7) * 132 + ((int)blockIdx.x >> 3);
  int bi2 = (int)(2.0f * (32.0f - sqrtf(fmaxf(0.f, 1024.0f - (float)tb))));
  if (bi2 > 63) bi2 = 63;
  while (bi2 > 0 && tb < tile0(bi2)) --bi2;
  while (tb >= tile0(bi2 + 1)) ++bi2;
  const int jlo = bi2 >> 1;
  const int bj2 = jlo + (tb - tile0(bi2));

  __shared__ char Asm[128 * 128];       // 16KB (fp8 rows = 128B = 8 slots)
  __shared__ char Bsm[256 * 128];       // 32KB
  __shared__ float2 red2[4][128];       // 4KB        total 52KB

  const int t    = threadIdx.x;
  const int lane = t & 63, wave = t >> 6;
  const int li   = lane & 15, hi = lane >> 4;
  const int wr   = wave >> 2, wc = wave & 3;   // 2x4 wave grid
  const int i0   = bi2 * 128, j0 = bj2 * 256;

  const char* gA = nb + (size_t)i0 * 128;
  const char* gB = nb + (size_t)j0 * 128;

  // ---- stage: linear LDS dest, inverse-swizzled global source ----
  #pragma unroll
  for (int it = 0; it < 2; ++it) {
    int e = it * 512 + t, r = e >> 3, sl = e & 7, sg = sl ^ (r & 7);
    __builtin_amdgcn_global_load_lds(
        (const AS1 void*)(gA + (size_t)r * 128 + sg * 16),
        (AS3 void*)(Asm + e * 16), 16, 0, 0);
  }
  #pragma unroll
  for (int it = 0; it < 4; ++it) {
    int e = it * 512 + t, r = e >> 3, sl = e & 7, sg = sl ^ (r & 7);
    __builtin_amdgcn_global_load_lds(
        (const AS1 void*)(gB + (size_t)r * 128 + sg * 16),
        (AS3 void*)(Bsm + e * 16), 16, 0, 0);
  }

  f32x4 acc[4][4];
  #pragma unroll
  for (int m = 0; m < 4; ++m)
    #pragma unroll
    for (int n = 0; n < 4; ++n) acc[m][n] = (f32x4){0.f, 0.f, 0.f, 0.f};

  asm volatile("s_waitcnt vmcnt(0)" ::: "memory");
  __builtin_amdgcn_s_barrier();
  __builtin_amdgcn_sched_barrier(0);

  // ---- A fragments: lane row = l&15, k = (l>>4)*32 + [0..32) ----
  i32x8 af[4];
  #pragma unroll
  for (int m = 0; m < 4; ++m) {
    const int R = wr * 64 + m * 16 + li, rb = R & 7;
    i32x4 lo = *(const i32x4*)(Asm + (size_t)R * 128 + (((hi << 1)    ) ^ rb) * 16);
    i32x4 hv = *(const i32x4*)(Asm + (size_t)R * 128 + (((hi << 1) | 1) ^ rb) * 16);
    af[m][0] = lo[0]; af[m][1] = lo[1]; af[m][2] = lo[2]; af[m][3] = lo[3];
    af[m][4] = hv[0]; af[m][5] = hv[1]; af[m][6] = hv[2]; af[m][7] = hv[3];
  }

  __builtin_amdgcn_s_setprio(1);
  #pragma unroll
  for (int n = 0; n < 4; ++n) {
    const int R = wc * 64 + n * 16 + li, rb = R & 7;
    i32x4 lo = *(const i32x4*)(Bsm + (size_t)R * 128 + (((hi << 1)    ) ^ rb) * 16);
    i32x4 hv = *(const i32x4*)(Bsm + (size_t)R * 128 + (((hi << 1) | 1) ^ rb) * 16);
    i32x8 bfr;
    bfr[0] = lo[0]; bfr[1] = lo[1]; bfr[2] = lo[2]; bfr[3] = lo[3];
    bfr[4] = hv[0]; bfr[5] = hv[1]; bfr[6] = hv[2]; bfr[7] = hv[3];
    #pragma unroll
    for (int m = 0; m < 4; ++m)
      acc[m][n] = __builtin_amdgcn_mfma_scale_f32_16x16x128_f8f6f4(
          af[m], bfr, acc[m][n], 0, 0,   // cbsz=0 (fp8 e4m3), blgp=0 (fp8)
          0, 127,                        // opselA, scaleA = e8m0(127) = 1.0
          0, 127);                       // opselB, scaleB = 1.0
  }
  __builtin_amdgcn_s_setprio(0);

  // ---- epilogue: bucket sums, DPP reduce, cross-wave combine ----
  const bool isdiag = (bj2 == jlo);
  const bool ispost = (bj2 == jlo + 16);
  const bool special = isdiag | ispost;
  const unsigned jw0 = (unsigned)(j0 + wc * 64);

  #pragma unroll
  for (int m = 0; m < 4; ++m) {
    const uint4 T4 = *(const uint4*)(Trow + i0 + wr * 64 + m * 16 + hi * 4);
    const unsigned Ts[4] = {T4.x, T4.y, T4.z, T4.w};
    #pragma unroll
    for (int rg = 0; rg < 4; ++rg) {
      const unsigned i = (unsigned)(i0 + wr * 64 + m * 16 + hi * 4 + rg);
      const unsigned T = Ts[rg];
      float r0, r1;
      if (special) {
        float s0 = 0.f, s1 = 0.f;
        #pragma unroll
        for (int n = 0; n < 4; ++n) {
          const unsigned j = jw0 + n * 16 + (unsigned)li;
          const bool ip = ispost && (j == i + B_);
          if (ip) posl[i] = 2.0f * acc[m][n][rg];
          if ((j > i) && !ip) {
            float e = __expf(2.0f * acc[m][n][rg]);
            if (j < T) s0 += e; else s1 += e;
          }
        }
        r0 = rsum16(s0); r1 = rsum16(s1);
      } else if ((T > jw0) && (T < jw0 + 64u)) {   // straddle (rare)
        float s0 = 0.f, s1 = 0.f;
        #pragma unroll
        for (int n = 0; n < 4; ++n) {
          const unsigned j = jw0 + n * 16 + (unsigned)li;
          float e = __expf(2.0f * acc[m][n][rg]);
          if (j < T) s0 += e; else s1 += e;
        }
        r0 = rsum16(s0); r1 = rsum16(s1);
      } else {                                      // uniform bucket: 1 reduce
        float s = 0.f;
        #pragma unroll
        for (int n = 0; n < 4; ++n) s += __expf(2.0f * acc[m][n][rg]);
        s = rsum16(s);
        const bool lo = (T > jw0);
        r0 = lo ? s : 0.f;
        r1 = lo ? 0.f : s;
      }
      if (li == 0)
        red2[wc][wr * 64 + m * 16 + hi * 4 + rg] = make_float2(r0, r1);
    }
  }
  __syncthreads();

  if (t < 128) {
    float2 s = make_float2(0.f, 0.f);
    #pragma unroll
    for (int w = 0; w < 4; ++w) {
      float2 v = red2[w][t];
      s.x += v.x; s.y += v.y;
    }
    part[(size_t)tb * 128 + t] = s;
  }
}

// ---------------------------------------------------------------------------
// Kernel C: fused rowreduce + finalize, ATOMIC-LIGHT (R22 rewrite).
// 64 blocks x 256 threads. Panel blocks: reduce part slots -> per-row sums,
// PLAIN-VALUE agent-scope atomic stores to rowsum[8192] (no global E RMWs).
// Last block (fence+counter, R6-proven): builds buckets in LDS from rowsum
// (8192 coalesced u64 atomic loads + 16K fast LDS atomics — R3-proven
// finalize logic), then computes the loss directly from LDS.
// ---------------------------------------------------------------------------
__global__ __launch_bounds__(256) void nt_rowfin(
    const float2* __restrict__ part, const float* __restrict__ posl,
    float2* __restrict__ rowsum, unsigned* __restrict__ counter,
    float* __restrict__ out) {
  __shared__ float2 xch[128];
  __shared__ int lastflag;
  __shared__ float Eb[4104];     // buckets (last block only)
  __shared__ double red[256];
  const int bi2 = (int)blockIdx.x;             // 0..63 == row panel
  const int t = threadIdx.x;
  const int lrow = t & 127, sh = t >> 7;
  const int base = tile0(bi2);
  const int cnt  = 32 - (bi2 >> 1);

  float2 s = make_float2(0.f, 0.f);
  for (int c = sh; c < cnt; c += 2) {
    float2 v = part[(size_t)(base + c) * 128 + lrow];
    s.x += v.x; s.y += v.y;
  }
  if (sh == 1) xch[lrow] = s;
  __syncthreads();
  if (sh == 0) {
    float2 v = xch[lrow];
    s.x += v.x; s.y += v.y;
    union { float2 f; unsigned long long u; } cv; cv.f = s;
    __hip_atomic_store((unsigned long long*)(rowsum + bi2 * 128 + lrow),
                       cv.u, __ATOMIC_RELAXED, __HIP_MEMORY_SCOPE_AGENT);
  }
  __threadfence();
  __syncthreads();
  if (t == 0) lastflag = (atomicAdd(counter, 1u) == 63u) ? 1 : 0;
  __syncthreads();
  if (!lastflag) return;

  // ---- last block: build buckets in LDS, then the loss ----
  __threadfence();
  for (int r = t; r < 4104; r += 256) Eb[r] = 0.f;
  __syncthreads();
  for (int i = t; i < (int)N_; i += 256) {
    unsigned long long raw = __hip_atomic_load(
        (const unsigned long long*)(rowsum + i),
        __ATOMIC_RELAXED, __HIP_MEMORY_SCOPE_AGENT);
    union { unsigned long long u; float2 f; } cv; cv.u = raw;
    const unsigned rlo = rowS((unsigned)i) / M_;
    atomicAdd(&Eb[rlo],      cv.f.x);   // LDS atomics: on-CU, cheap
    atomicAdd(&Eb[rlo + 1u], cv.f.y);
  }
  __syncthreads();

  double acc = 0.0;
  for (int r = t; r < (int)B_; r += 256) {
    float pl = posl[r];
    acc += (double)(logf(__expf(pl) + Eb[r]) - pl);
  }
  red[t] = acc;
  __syncthreads();
  for (int m = 128; m > 0; m >>= 1) {
    if (t < m) red[t] += red[t + m];
    __syncthreads();
  }
  if (t == 0) out[0] = (float)(red[0] / (double)B_);
}

// ---------------------------------------------------------------------------
extern "C" void kernel_launch(void* const* d_in, const int* in_sizes, int n_in,
                              void* d_out, int out_size, void* d_ws, size_t ws_size,
                              hipStream_t stream) {
  const float* zis = (const float*)d_in[0];
  const float* zjs = (const float*)d_in[1];
  float* out = (float*)d_out;

  char* ws = (char*)d_ws;
  char*     nb      = ws;                                  // 8192*128 fp8 = 1 MB
  unsigned* Trow    = (unsigned*)(ws + 1048576);           // 32 KB
  float*    posl    = (float*)(ws + 1081344);              // 16 KB
  float2*   part    = (float2*)(ws + 1097728);             // 1056*128*8 = 1.08 MB
  float2*   rowsum  = (float2*)(ws + 2179072);             // 8192 float2 = 64 KB
  unsigned* counter = (unsigned*)(ws + 2244608);           // 1 u32

  nt_norm  <<<dim3(N_ / 8), 256, 0, stream>>>(zis, zjs, (unsigned*)nb, Trow, counter);
  nt_gemm  <<<dim3(NT2_),   512, 0, stream>>>(nb, Trow, part, posl);
  nt_rowfin<<<dim3(64),     256, 0, stream>>>(part, posl, rowsum, counter, out);
}

// Round 23
// 45.903 us; speedup vs baseline: 1.4803x; 1.4803x over previous
//
#include <hip/hip_runtime.h>
#include <hip/hip_bf16.h>
#include <math.h>

#define B_  4096u
#define N_  8192
#define D_  128
#define M_  8190u          // negatives per logits row = 2B-2
#define SB_ 25159680u      // S_B = B*(2B-2) - B*(B-1)/2
#define NT2_ 1056          // upper-tri 128x256 tiles

#define AS1 __attribute__((address_space(1)))
#define AS3 __attribute__((address_space(3)))

typedef __attribute__((ext_vector_type(8))) int   i32x8;
typedef __attribute__((ext_vector_type(4))) int   i32x4;
typedef __attribute__((ext_vector_type(4))) float f32x4;

// cumulative flat-count of strict-upper (minus positives) elements before row i
static __device__ __forceinline__ unsigned rowS(unsigned i) {
  if (i <= B_) return i * (2u * B_ - 2u) - (i * (i - 1u)) / 2u;
  unsigned d = i - B_;
  return SB_ + d * (B_ - 1u) - (d * (d - 1u)) / 2u;
}
// cumulative tile count before row-panel m (128-row panels, 256-col tiles)
static __device__ __forceinline__ int tile0(int m) {
  return 32 * m - (m * m - 2 * m + (m & 1)) / 4;
}
// 16-lane DPP row_ror rotation reduce (validated R7/R8)
template <int CTRL>
static __device__ __forceinline__ float dpp_add(float x) {
  union { float f; int i; } u, r;
  u.f = x;
  r.i = __builtin_amdgcn_mov_dpp(u.i, CTRL, 0xF, 0xF, 0);
  return x + r.f;
}
static __device__ __forceinline__ float rsum16(float x) {
  x = dpp_add<0x121>(x);
  x = dpp_add<0x122>(x);
  x = dpp_add<0x124>(x);
  x = dpp_add<0x128>(x);
  return x;
}

// ---------------------------------------------------------------------------
// Kernel A: normalize rows of reps=[zjs;zis] -> fp8 e4m3 nb[row][k] (1 MB);
// build Trow; block 0 zeroes E buckets + completion counter (replay-safe).
// (byte-identical to R19)
// ---------------------------------------------------------------------------
__global__ __launch_bounds__(256) void nt_norm(
    const float* __restrict__ zis, const float* __restrict__ zjs,
    unsigned* __restrict__ nb8, unsigned* __restrict__ Trow,
    unsigned* __restrict__ zbase) {
  const int t   = threadIdx.x;
  const int row = blockIdx.x * 8 + (t >> 5);
  const int c   = t & 31;
  const float* src = (row < (int)B_) ? (zjs + (size_t)row * D_)
                                     : (zis + (size_t)(row - (int)B_) * D_);
  float4 v = *(const float4*)(src + c * 4);
  float s = v.x * v.x + v.y * v.y + v.z * v.z + v.w * v.w;
  #pragma unroll
  for (int m = 16; m >= 1; m >>= 1) s += __shfl_xor(s, m, 32);
  float rn = 1.0f / fmaxf(sqrtf(s), 1e-8f);
  int p = __builtin_amdgcn_cvt_pk_fp8_f32(v.x * rn, v.y * rn, 0, false);
  p     = __builtin_amdgcn_cvt_pk_fp8_f32(v.z * rn, v.w * rn, p, true);
  nb8[(size_t)row * 32 + c] = (unsigned)p;

  if (t < 8) {
    unsigned i   = (unsigned)(blockIdx.x * 8 + t);
    unsigned S   = rowS(i);
    unsigned rlo = S / M_;
    unsigned Sh  = (rlo + 1u) * M_;
    unsigned jt  = Sh - S + i + 1u;
    Trow[i] = jt + ((i < B_ && jt > i + B_) ? 1u : 0u);
  }
  if (blockIdx.x == 0) {
    for (int r = t; r < 4128; r += 256) zbase[r] = 0u;
  }
}

// ---------------------------------------------------------------------------
// Kernel B: 128x256-tile upper-tri Gram via MX-scaled fp8 MFMA
// (byte-identical to R15/R19 — proven best, measured 19.0 us steady-state).
// ---------------------------------------------------------------------------
__global__ __launch_bounds__(512, 4) void nt_gemm(
    const char* __restrict__ nb, const unsigned* __restrict__ Trow,
    float2* __restrict__ part, float* __restrict__ posl) {
  // XCD-chunked bijective swizzle: 1056 = 8 * 132
  const int tb = ((int)blockIdx.x & 7) * 132 + ((int)blockIdx.x >> 3);
  int bi2 = (int)(2.0f * (32.0f - sqrtf(fmaxf(0.f, 1024.0f - (float)tb))));
  if (bi2 > 63) bi2 = 63;
  while (bi2 > 0 && tb < tile0(bi2)) --bi2;
  while (tb >= tile0(bi2 + 1)) ++bi2;
  const int jlo = bi2 >> 1;
  const int bj2 = jlo + (tb - tile0(bi2));

  __shared__ char Asm[128 * 128];       // 16KB (fp8 rows = 128B = 8 slots)
  __shared__ char Bsm[256 * 128];       // 32KB
  __shared__ float2 red2[4][128];       // 4KB        total 52KB

  const int t    = threadIdx.x;
  const int lane = t & 63, wave = t >> 6;
  const int li   = lane & 15, hi = lane >> 4;
  const int wr   = wave >> 2, wc = wave & 3;   // 2x4 wave grid
  const int i0   = bi2 * 128, j0 = bj2 * 256;

  const char* gA = nb + (size_t)i0 * 128;
  const char* gB = nb + (size_t)j0 * 128;

  // ---- stage: linear LDS dest, inverse-swizzled global source ----
  #pragma unroll
  for (int it = 0; it < 2; ++it) {
    int e = it * 512 + t, r = e >> 3, sl = e & 7, sg = sl ^ (r & 7);
    __builtin_amdgcn_global_load_lds(
        (const AS1 void*)(gA + (size_t)r * 128 + sg * 16),
        (AS3 void*)(Asm + e * 16), 16, 0, 0);
  }
  #pragma unroll
  for (int it = 0; it < 4; ++it) {
    int e = it * 512 + t, r = e >> 3, sl = e & 7, sg = sl ^ (r & 7);
    __builtin_amdgcn_global_load_lds(
        (const AS1 void*)(gB + (size_t)r * 128 + sg * 16),
        (AS3 void*)(Bsm + e * 16), 16, 0, 0);
  }

  f32x4 acc[4][4];
  #pragma unroll
  for (int m = 0; m < 4; ++m)
    #pragma unroll
    for (int n = 0; n < 4; ++n) acc[m][n] = (f32x4){0.f, 0.f, 0.f, 0.f};

  asm volatile("s_waitcnt vmcnt(0)" ::: "memory");
  __builtin_amdgcn_s_barrier();
  __builtin_amdgcn_sched_barrier(0);

  // ---- A fragments: lane row = l&15, k = (l>>4)*32 + [0..32) ----
  i32x8 af[4];
  #pragma unroll
  for (int m = 0; m < 4; ++m) {
    const int R = wr * 64 + m * 16 + li, rb = R & 7;
    i32x4 lo = *(const i32x4*)(Asm + (size_t)R * 128 + (((hi << 1)    ) ^ rb) * 16);
    i32x4 hv = *(const i32x4*)(Asm + (size_t)R * 128 + (((hi << 1) | 1) ^ rb) * 16);
    af[m][0] = lo[0]; af[m][1] = lo[1]; af[m][2] = lo[2]; af[m][3] = lo[3];
    af[m][4] = hv[0]; af[m][5] = hv[1]; af[m][6] = hv[2]; af[m][7] = hv[3];
  }

  __builtin_amdgcn_s_setprio(1);
  #pragma unroll
  for (int n = 0; n < 4; ++n) {
    const int R = wc * 64 + n * 16 + li, rb = R & 7;
    i32x4 lo = *(const i32x4*)(Bsm + (size_t)R * 128 + (((hi << 1)    ) ^ rb) * 16);
    i32x4 hv = *(const i32x4*)(Bsm + (size_t)R * 128 + (((hi << 1) | 1) ^ rb) * 16);
    i32x8 bfr;
    bfr[0] = lo[0]; bfr[1] = lo[1]; bfr[2] = lo[2]; bfr[3] = lo[3];
    bfr[4] = hv[0]; bfr[5] = hv[1]; bfr[6] = hv[2]; bfr[7] = hv[3];
    #pragma unroll
    for (int m = 0; m < 4; ++m)
      acc[m][n] = __builtin_amdgcn_mfma_scale_f32_16x16x128_f8f6f4(
          af[m], bfr, acc[m][n], 0, 0,   // cbsz=0 (fp8 e4m3), blgp=0 (fp8)
          0, 127,                        // opselA, scaleA = e8m0(127) = 1.0
          0, 127);                       // opselB, scaleB = 1.0
  }
  __builtin_amdgcn_s_setprio(0);

  // ---- epilogue: bucket sums, DPP reduce, cross-wave combine ----
  const bool isdiag = (bj2 == jlo);
  const bool ispost = (bj2 == jlo + 16);
  const bool special = isdiag | ispost;
  const unsigned jw0 = (unsigned)(j0 + wc * 64);

  #pragma unroll
  for (int m = 0; m < 4; ++m) {
    const uint4 T4 = *(const uint4*)(Trow + i0 + wr * 64 + m * 16 + hi * 4);
    const unsigned Ts[4] = {T4.x, T4.y, T4.z, T4.w};
    #pragma unroll
    for (int rg = 0; rg < 4; ++rg) {
      const unsigned i = (unsigned)(i0 + wr * 64 + m * 16 + hi * 4 + rg);
      const unsigned T = Ts[rg];
      float r0, r1;
      if (special) {
        float s0 = 0.f, s1 = 0.f;
        #pragma unroll
        for (int n = 0; n < 4; ++n) {
          const unsigned j = jw0 + n * 16 + (unsigned)li;
          const bool ip = ispost && (j == i + B_);
          if (ip) posl[i] = 2.0f * acc[m][n][rg];
          if ((j > i) && !ip) {
            float e = __expf(2.0f * acc[m][n][rg]);
            if (j < T) s0 += e; else s1 += e;
          }
        }
        r0 = rsum16(s0); r1 = rsum16(s1);
      } else if ((T > jw0) && (T < jw0 + 64u)) {   // straddle (rare)
        float s0 = 0.f, s1 = 0.f;
        #pragma unroll
        for (int n = 0; n < 4; ++n) {
          const unsigned j = jw0 + n * 16 + (unsigned)li;
          float e = __expf(2.0f * acc[m][n][rg]);
          if (j < T) s0 += e; else s1 += e;
        }
        r0 = rsum16(s0); r1 = rsum16(s1);
      } else {                                      // uniform bucket: 1 reduce
        float s = 0.f;
        #pragma unroll
        for (int n = 0; n < 4; ++n) s += __expf(2.0f * acc[m][n][rg]);
        s = rsum16(s);
        const bool lo = (T > jw0);
        r0 = lo ? s : 0.f;
        r1 = lo ? 0.f : s;
      }
      if (li == 0)
        red2[wc][wr * 64 + m * 16 + hi * 4 + rg] = make_float2(r0, r1);
    }
  }
  __syncthreads();

  if (t < 128) {
    float2 s = make_float2(0.f, 0.f);
    #pragma unroll
    for (int w = 0; w < 4; ++w) {
      float2 v = red2[w][t];
      s.x += v.x; s.y += v.y;
    }
    part[(size_t)tb * 128 + t] = s;
  }
}

// ---------------------------------------------------------------------------
// Kernel C: fused rowreduce + finalize (R19 base) + R23 delta: PER-PANEL LDS
// PRE-AGGREGATION. A panel's rows span <=131 buckets (tail panels: ~4), so
// rows first LDS-atomicAdd into a local bucket window, then ONE global
// atomicAdd per distinct nonzero bucket (16K global RMWs -> ~4.2K; tail-
// panel same-line contention 256 -> ~6). Fence+counter chain and last-block
// finalize (relaxed atomic loads) unchanged from R19.
// ---------------------------------------------------------------------------
__global__ __launch_bounds__(256) void nt_rowfin(
    const float2* __restrict__ part, const float* __restrict__ posl,
    float* __restrict__ E, unsigned* __restrict__ counter,
    float* __restrict__ out) {
  __shared__ float2 xch[128];
  __shared__ float Epan[132];
  __shared__ int lastflag;
  __shared__ double red[256];
  const int bi2 = (int)blockIdx.x;             // 0..63 == row panel
  const int t = threadIdx.x;
  const int lrow = t & 127, sh = t >> 7;
  const int base = tile0(bi2);
  const int cnt  = 32 - (bi2 >> 1);
  const unsigned i0     = (unsigned)(bi2 * 128);
  const unsigned rstart = rowS(i0) / M_;
  const unsigned rspan  = rowS(i0 + 127u) / M_ + 1u - rstart + 1u; // <=131

  if (t < 132) Epan[t] = 0.f;

  float2 s = make_float2(0.f, 0.f);
  for (int c = sh; c < cnt; c += 2) {
    float2 v = part[(size_t)(base + c) * 128 + lrow];
    s.x += v.x; s.y += v.y;
  }
  if (sh == 1) xch[lrow] = s;
  __syncthreads();
  if (sh == 0) {
    float2 v = xch[lrow];
    s.x += v.x; s.y += v.y;
    const unsigned i   = i0 + (unsigned)lrow;
    const unsigned rlo = rowS(i) / M_;
    atomicAdd(&Epan[rlo - rstart],      s.x);   // LDS atomics: on-CU
    atomicAdd(&Epan[rlo - rstart + 1u], s.y);
  }
  __syncthreads();
  if (t < (int)rspan) {
    float v = Epan[t];
    if (v != 0.f) atomicAdd(&E[rstart + (unsigned)t], v);
  }
  __threadfence();
  __syncthreads();
  if (t == 0) lastflag = (atomicAdd(counter, 1u) == 63u) ? 1 : 0;
  __syncthreads();
  if (!lastflag) return;

  // ---- last block: loss = (1/B) * sum_r ( log(exp(posl)+E[r]) - posl[r] )
  __threadfence();
  double acc = 0.0;
  for (int r = t; r < (int)B_; r += 256) {
    float ev = __hip_atomic_load(&E[r], __ATOMIC_RELAXED,
                                 __HIP_MEMORY_SCOPE_AGENT);
    float pl = posl[r];
    acc += (double)(logf(__expf(pl) + ev) - pl);
  }
  red[t] = acc;
  __syncthreads();
  for (int m = 128; m > 0; m >>= 1) {
    if (t < m) red[t] += red[t + m];
    __syncthreads();
  }
  if (t == 0) out[0] = (float)(red[0] / (double)B_);
}

// ---------------------------------------------------------------------------
extern "C" void kernel_launch(void* const* d_in, const int* in_sizes, int n_in,
                              void* d_out, int out_size, void* d_ws, size_t ws_size,
                              hipStream_t stream) {
  const float* zis = (const float*)d_in[0];
  const float* zjs = (const float*)d_in[1];
  float* out = (float*)d_out;

  char* ws = (char*)d_ws;
  char*     nb      = ws;                                  // 8192*128 fp8 = 1 MB
  unsigned* Trow    = (unsigned*)(ws + 1048576);           // 32 KB
  float*    posl    = (float*)(ws + 1081344);              // 16 KB
  float2*   part    = (float2*)(ws + 1097728);             // 1056*128*8 = 1.08 MB
  float*    E       = (float*)(ws + 2179072);              // 4112 f32
  unsigned* counter = (unsigned*)(ws + 2195520);           // 1 u32
  unsigned* zb      = (unsigned*)E;                        // E+counter contiguous

  nt_norm  <<<dim3(N_ / 8), 256, 0, stream>>>(zis, zjs, (unsigned*)nb, Trow, zb);
  nt_gemm  <<<dim3(NT2_),   512, 0, stream>>>(nb, Trow, part, posl);
  nt_rowfin<<<dim3(64),     256, 0, stream>>>(part, posl, E, counter, out);
}